// Round 6
// baseline (761.448 us; speedup 1.0000x reference)
//
#include <hip/hip_runtime.h>

#define N_CTX 2048
#define DHEAD 64
#define SCALE_F 0.125f
#define EPS_F 1e-6f
#define KT 64
#define NSTEP (N_CTX / (2 * KT))   // 16 double-steps (2 tiles per step)
#define QBLK 256                   // q per block: 2 halves x 4 waves x 64 q

typedef __attribute__((ext_vector_type(8))) short short8;
typedef __attribute__((ext_vector_type(4))) float float4v;
typedef __attribute__((ext_vector_type(2))) unsigned uint2v;
typedef __attribute__((ext_vector_type(4))) unsigned uint4v;

// ---- bf16 pack: HW cvt_pk on device, parse-only fallback for host pass ----
#if defined(__HIP_DEVICE_COMPILE__) && __has_builtin(__builtin_amdgcn_cvt_pk_bf16_f32)
typedef __attribute__((ext_vector_type(2))) __bf16 bf16x2;
__device__ __forceinline__ unsigned pack2(float a, float b) {
    union { bf16x2 v; unsigned u; } x;
    x.v = __builtin_amdgcn_cvt_pk_bf16_f32(a, b);
    return x.u;
}
#else
__device__ __forceinline__ unsigned bf1(float f) {
    union { float f; unsigned u; } x; x.f = f;
    return (x.u + 0x7FFFu + ((x.u >> 16) & 1u)) >> 16;
}
__device__ __forceinline__ unsigned pack2(float a, float b) {
    return bf1(a) | (bf1(b) << 16);
}
#endif

// ---- gfx950 permlane swaps (K=16 C-layout -> K=32 A-frag re-tile) ----
#if defined(__HIP_DEVICE_COMPILE__) && __has_builtin(__builtin_amdgcn_permlane32_swap)
__device__ __forceinline__ void pl32(unsigned &x, unsigned &y) {
    uint2v r = __builtin_amdgcn_permlane32_swap(x, y, false, false);
    x = r[0]; y = r[1];
}
#else
__device__ __forceinline__ void pl32(unsigned &x, unsigned &y) {
    asm volatile("v_permlane32_swap_b32 %0, %1" : "+v"(x), "+v"(y));
}
#endif
#if defined(__HIP_DEVICE_COMPILE__) && __has_builtin(__builtin_amdgcn_permlane16_swap)
__device__ __forceinline__ void pl16(unsigned &x, unsigned &y) {
    uint2v r = __builtin_amdgcn_permlane16_swap(x, y, false, false);
    x = r[0]; y = r[1];
}
#else
__device__ __forceinline__ void pl16(unsigned &x, unsigned &y) {
    asm volatile("v_permlane16_swap_b32 %0, %1" : "+v"(x), "+v"(y));
}
#endif

// ---- LDS XOR swizzle (T2 / G4): unpadded [64][64] bf16 tiles (128B rows) ----
__device__ __forceinline__ int swz(int row, int col) {
    return col ^ ((row & 7) << 3);
}

// Layouts (gfx950, m89-verified):
//  mfma 16x16x32: A[m=lane&15][k=8q+j], B[k=8q+j][n=lane&15], C[row=4q+r][col=lane&15]
// S^T = K*Q^T (M=kv,N=q,K=d): lane(c,qd) holds S^T[kv][q=c].
// Square in regs -> permlane re-tile -> K=32 PV; denominator via ones-column
// register-constant B operand.
//
// R6 vs R5(115.7us): kv-SPLIT TLP. 512 threads: waves 0-3 do even kv-tiles,
// waves 4-7 odd tiles (same q ranges, partial O/den, cross-half LDS reduce
// at end). Per-CU LDS traffic / MFMA / VALU / staging / barriers UNCHANGED;
// waves/SIMD 2 -> 4. This is the controlled TLP experiment R1 wasn't (R1
// duplicated LDS reads 2x). Falsifier: dur>=110us kills the latency theory.

__global__ __launch_bounds__(512, 4)
void powsm_attn(const float* __restrict__ qg, const float* __restrict__ kg,
                const float* __restrict__ vg, float* __restrict__ og)
{
    __shared__ __align__(16) short KsB[2][64][64];  // [tile-parity][kv][d] swizzled
    __shared__ __align__(16) short VtB[2][64][64];  // [tile-parity][d][kv] swizzled
    __shared__ float Dn[8][64];                     // per-wave partial denominators

    const int bh   = blockIdx.y;
    const int tid  = threadIdx.x;
    const int wave = tid >> 6;     // 0..7
    const int lane = tid & 63;
    const int qd   = lane >> 4;    // quad 0..3
    const int c    = lane & 15;
    const int qgrp = wave & 3;     // q-group 0..3 (64 q each)
    const int half = wave >> 2;    // 0: even tiles, 1: odd tiles

    const size_t base = (size_t)bh * N_CTX * DHEAD;
    const float* qp = qg + base;
    const float* kp = kg + base;
    const float* vp = vg + base;
    float*       op = og + base;

    const int qw0 = blockIdx.x * QBLK + qgrp * 64;

    // ---- denominator B-frag: B[k][n=c] = (c==0) ? 1.0bf16 : 0 ----
    union { uint4v u; short8 s; } dvu;
    {
        const unsigned ob = (c == 0) ? 0x3F803F80u : 0u;
        dvu.u[0] = ob; dvu.u[1] = ob; dvu.u[2] = ob; dvu.u[3] = ob;
    }
    const short8 bfden = dvu.s;

    // ---- hoist Q B-frags (16x16x32), SCALE folded in ----
    short8 Qf[4][2];
    #pragma unroll
    for (int qt = 0; qt < 4; ++qt) {
        #pragma unroll
        for (int ks = 0; ks < 2; ++ks) {
            const float* src = qp + (size_t)(qw0 + qt*16 + c) * DHEAD + ks*32 + qd*8;
            float4v a = *(const float4v*)(src);
            float4v b = *(const float4v*)(src + 4);
            uint4v u;
            u[0] = pack2(a[0]*SCALE_F, a[1]*SCALE_F);
            u[1] = pack2(a[2]*SCALE_F, a[3]*SCALE_F);
            u[2] = pack2(b[0]*SCALE_F, b[1]*SCALE_F);
            u[3] = pack2(b[2]*SCALE_F, b[3]*SCALE_F);
            union { uint4v u; short8 s; } cv; cv.u = u;
            Qf[qt][ks] = cv.s;
        }
    }

    float4v Oacc[4][4];            // [qt][nt] partial (this half's tiles)
    #pragma unroll
    for (int qt = 0; qt < 4; ++qt)
        #pragma unroll
        for (int nt = 0; nt < 4; ++nt)
            Oacc[qt][nt] = (float4v){0.f, 0.f, 0.f, 0.f};
    float4v Oden[4];               // partial denominator C-frag (col 0)
    #pragma unroll
    for (int qt = 0; qt < 4; ++qt) Oden[qt] = (float4v){0.f, 0.f, 0.f, 0.f};

    // ---- staging role: threads 0-255 stage buffer 0 (even tile),
    //      threads 256-511 stage buffer 1 (odd tile) ----
    const int g  = tid >> 8;       // buffer / tile parity staged by this thread
    const int st = tid & 255;
    const int kr = st >> 4;        // 0..15
    const int kc = st & 15;        // 0..15

    float4v pK[4], pV[4];
    // ---- prologue: load + stage tile g into buffer g ----
    {
        const float* k0 = kp + (size_t)g * KT * DHEAD;
        const float* v0 = vp + (size_t)g * KT * DHEAD;
        #pragma unroll
        for (int u = 0; u < 4; ++u)
            pK[u] = *(const float4v*)(k0 + (size_t)(kr + u*16) * DHEAD + kc*4);
        #pragma unroll
        for (int j = 0; j < 4; ++j)
            pV[j] = *(const float4v*)(v0 + (size_t)(4*kr + j) * DHEAD + kc*4);
        short (*Ks)[64] = KsB[g];
        short (*Vt)[64] = VtB[g];
        #pragma unroll
        for (int u = 0; u < 4; ++u) {
            const int row = kr + u*16;
            uint2v w; w[0] = pack2(pK[u][0], pK[u][1]); w[1] = pack2(pK[u][2], pK[u][3]);
            *(uint2v*)&Ks[row][swz(row, kc*4)] = w;
        }
        #pragma unroll
        for (int kk = 0; kk < 4; ++kk) {
            const int row = 4*kc + kk;
            uint2v w; w[0] = pack2(pV[0][kk], pV[1][kk]); w[1] = pack2(pV[2][kk], pV[3][kk]);
            *(uint2v*)&Vt[row][swz(row, 4*kr)] = w;
        }
    }
    __syncthreads();

    #pragma unroll 1
    for (int t = 0; t < NSTEP; ++t) {
        // ---- issue next-step loads early (land during compute) ----
        if (t + 1 < NSTEP) {
            const float* kn = kp + (size_t)(2*(t+1) + g) * KT * DHEAD;
            const float* vn = vp + (size_t)(2*(t+1) + g) * KT * DHEAD;
            #pragma unroll
            for (int u = 0; u < 4; ++u)
                pK[u] = *(const float4v*)(kn + (size_t)(kr + u*16) * DHEAD + kc*4);
            #pragma unroll
            for (int j = 0; j < 4; ++j)
                pV[j] = *(const float4v*)(vn + (size_t)(4*kr + j) * DHEAD + kc*4);
        }

        // ---- compute this half's tile (2t+half) from buffer [half] ----
        short (*Ks)[64] = KsB[half];
        short (*Vt)[64] = VtB[half];
        #pragma unroll
        for (int blk = 0; blk < 2; ++blk) {
            float4v slo[4], shi[4];
            #pragma unroll
            for (int qt = 0; qt < 4; ++qt) {
                slo[qt] = (float4v){0.f, 0.f, 0.f, 0.f};
                shi[qt] = (float4v){0.f, 0.f, 0.f, 0.f};
            }
            #pragma unroll
            for (int ks = 0; ks < 2; ++ks) {
                short8 afl = *(const short8*)&Ks[blk*32 + c][swz(c, ks*32 + qd*8)];
                #pragma unroll
                for (int qt = 0; qt < 4; ++qt)
                    slo[qt] = __builtin_amdgcn_mfma_f32_16x16x32_bf16(afl, Qf[qt][ks], slo[qt], 0, 0, 0);
            }
            #pragma unroll
            for (int ks = 0; ks < 2; ++ks) {
                short8 afh = *(const short8*)&Ks[blk*32 + 16 + c][swz(c, ks*32 + qd*8)];
                #pragma unroll
                for (int qt = 0; qt < 4; ++qt)
                    shi[qt] = __builtin_amdgcn_mfma_f32_16x16x32_bf16(afh, Qf[qt][ks], shi[qt], 0, 0, 0);
            }
            // square (vectorized) + pack + K32 re-tile (4 permlanes per qt)
            short8 pa[4];
            #pragma unroll
            for (int qt = 0; qt < 4; ++qt) {
                float4v psl = slo[qt] * slo[qt];
                float4v psh = shi[qt] * shi[qt];
                unsigned w00 = pack2(psl[0], psl[1]);   // (h=0,u=0)
                unsigned w01 = pack2(psl[2], psl[3]);   // (h=0,u=1)
                unsigned w10 = pack2(psh[0], psh[1]);   // (h=1,u=0)
                unsigned w11 = pack2(psh[2], psh[3]);   // (h=1,u=1)
                pl32(w00, w10);                 // lane-bit5 <-> h
                pl32(w01, w11);
                pl16(w00, w10);                 // lane-bit4 <-> g_hi
                pl16(w01, w11);
                union { uint4v u; short8 s; } cv;
                cv.u[0] = w00; cv.u[1] = w01; cv.u[2] = w10; cv.u[3] = w11;
                pa[qt] = cv.s;
            }
            // denominator: Σ P into col 0 (register-constant B operand)
            #pragma unroll
            for (int qt = 0; qt < 4; ++qt)
                Oden[qt] = __builtin_amdgcn_mfma_f32_16x16x32_bf16(pa[qt], bfden, Oden[qt], 0, 0, 0);
            // PV at K=32
            #pragma unroll
            for (int nt = 0; nt < 4; ++nt) {
                short8 bf = *(const short8*)&Vt[nt*16 + c][swz(c, blk*32 + qd*8)];
                #pragma unroll
                for (int qt = 0; qt < 4; ++qt)
                    Oacc[qt][nt] = __builtin_amdgcn_mfma_f32_16x16x32_bf16(pa[qt], bf, Oacc[qt][nt], 0, 0, 0);
            }
        }
        __syncthreads();   // A: all reads of both buffers complete

        // ---- stage next step's tile into buffer g ----
        if (t + 1 < NSTEP) {
            short (*Kn)[64] = KsB[g];
            short (*Vn)[64] = VtB[g];
            #pragma unroll
            for (int u = 0; u < 4; ++u) {
                const int row = kr + u*16;
                uint2v w; w[0] = pack2(pK[u][0], pK[u][1]); w[1] = pack2(pK[u][2], pK[u][3]);
                *(uint2v*)&Kn[row][swz(row, kc*4)] = w;
            }
            #pragma unroll
            for (int kk = 0; kk < 4; ++kk) {
                const int row = 4*kc + kk;
                uint2v w; w[0] = pack2(pV[0][kk], pV[1][kk]); w[1] = pack2(pV[2][kk], pV[3][kk]);
                *(uint2v*)&Vn[row][swz(row, 4*kr)] = w;
            }
        }
        __syncthreads();   // B: writes visible
    }

    // ---- publish partial denominators (lanes c==0 hold col 0) ----
    if (c == 0) {
        #pragma unroll
        for (int qt = 0; qt < 4; ++qt)
            #pragma unroll
            for (int r = 0; r < 4; ++r)
                Dn[wave][qt*16 + qd*4 + r] = Oden[qt][r];
    }
    __syncthreads();

    // ---- cross-half O reduce: 2 rounds x 2 wave-pairs through LDS ----
    float* red0 = (float*)&KsB[0][0][0];   // 4096 floats
    float* red1 = (float*)&VtB[0][0][0];   // 4096 floats
    #pragma unroll 1
    for (int rnd = 0; rnd < 2; ++rnd) {
        if (half == 1 && (qgrp >> 1) == rnd) {
            float* buf = (qgrp & 1) ? red1 : red0;
            #pragma unroll
            for (int qt = 0; qt < 4; ++qt)
                #pragma unroll
                for (int nt = 0; nt < 4; ++nt)
                    #pragma unroll
                    for (int r = 0; r < 4; ++r)
                        buf[(qt*16 + qd*4 + r)*64 + nt*16 + c] = Oacc[qt][nt][r];
        }
        __syncthreads();
        if (half == 0 && (qgrp >> 1) == rnd) {
            float* buf = (qgrp & 1) ? red1 : red0;
            #pragma unroll
            for (int qt = 0; qt < 4; ++qt)
                #pragma unroll
                for (int nt = 0; nt < 4; ++nt)
                    #pragma unroll
                    for (int r = 0; r < 4; ++r)
                        Oacc[qt][nt][r] += buf[(qt*16 + qd*4 + r)*64 + nt*16 + c];
        }
        __syncthreads();
    }

    // ---- epilogue: even half normalizes and stores ----
    if (half == 0) {
        #pragma unroll
        for (int qt = 0; qt < 4; ++qt) {
            #pragma unroll
            for (int r = 0; r < 4; ++r) {
                const int idx = qt*16 + qd*4 + r;
                float dsum = Dn[qgrp][idx] + Dn[4 + qgrp][idx];
                float inv = 1.0f / (dsum + EPS_F);
                float* dst = op + (size_t)(qw0 + idx) * DHEAD + c;
                #pragma unroll
                for (int nt = 0; nt < 4; ++nt)
                    dst[nt*16] = Oacc[qt][nt][r] * inv;
            }
        }
    }
}

extern "C" void kernel_launch(void* const* d_in, const int* in_sizes, int n_in,
                              void* d_out, int out_size, void* d_ws, size_t ws_size,
                              hipStream_t stream) {
    const float* q = (const float*)d_in[0];
    const float* k = (const float*)d_in[1];
    const float* v = (const float*)d_in[2];
    float* out = (float*)d_out;
    dim3 grid(N_CTX / QBLK, 64, 1);   // (8 q-tiles, B*H) = 512 blocks = 2/CU
    powsm_attn<<<grid, dim3(512, 1, 1), 0, stream>>>(q, k, v, out);
}

// Round 7
// 213.771 us; speedup vs baseline: 3.5620x; 3.5620x over previous
//
#include <hip/hip_runtime.h>

#define N_CTX 2048
#define DHEAD 64
#define SCALE_F 0.125f
#define EPS_F 1e-6f
#define KT 128
#define NITER (N_CTX / KT)        // 16
#define QBLK 256                  // q per block: 4 waves x 64 q-rows

typedef __attribute__((ext_vector_type(8))) short short8;
typedef __attribute__((ext_vector_type(4))) float float4v;
typedef __attribute__((ext_vector_type(2))) unsigned uint2v;
typedef __attribute__((ext_vector_type(4))) unsigned uint4v;

// ---- bf16 pack: HW cvt_pk on device, parse-only fallback for host pass ----
#if defined(__HIP_DEVICE_COMPILE__) && __has_builtin(__builtin_amdgcn_cvt_pk_bf16_f32)
typedef __attribute__((ext_vector_type(2))) __bf16 bf16x2;
__device__ __forceinline__ unsigned pack2(float a, float b) {
    union { bf16x2 v; unsigned u; } x;
    x.v = __builtin_amdgcn_cvt_pk_bf16_f32(a, b);
    return x.u;
}
#else
__device__ __forceinline__ unsigned bf1(float f) {
    union { float f; unsigned u; } x; x.f = f;
    return (x.u + 0x7FFFu + ((x.u >> 16) & 1u)) >> 16;
}
__device__ __forceinline__ unsigned pack2(float a, float b) {
    return bf1(a) | (bf1(b) << 16);
}
#endif

// ---- gfx950 permlane swaps (K=16 C-layout -> K=32 A-frag re-tile) ----
#if defined(__HIP_DEVICE_COMPILE__) && __has_builtin(__builtin_amdgcn_permlane32_swap)
__device__ __forceinline__ void pl32(unsigned &x, unsigned &y) {
    uint2v r = __builtin_amdgcn_permlane32_swap(x, y, false, false);
    x = r[0]; y = r[1];
}
#else
__device__ __forceinline__ void pl32(unsigned &x, unsigned &y) {
    asm volatile("v_permlane32_swap_b32 %0, %1" : "+v"(x), "+v"(y));
}
#endif
#if defined(__HIP_DEVICE_COMPILE__) && __has_builtin(__builtin_amdgcn_permlane16_swap)
__device__ __forceinline__ void pl16(unsigned &x, unsigned &y) {
    uint2v r = __builtin_amdgcn_permlane16_swap(x, y, false, false);
    x = r[0]; y = r[1];
}
#else
__device__ __forceinline__ void pl16(unsigned &x, unsigned &y) {
    asm volatile("v_permlane16_swap_b32 %0, %1" : "+v"(x), "+v"(y));
}
#endif

// ---- LDS XOR swizzle (T2 / G4): short at (row,col) -> col ^ ((row&7)<<3).
// Swizzle bits >=3 keep 4/8-short aligned runs contiguous; all frag reads
// have row&7 == c&7 so 16-lane phase groups tile the banks.
__device__ __forceinline__ int swz(int row, int col) {
    return col ^ ((row & 7) << 3);
}

// Layouts (gfx950, m89-verified):
//  mfma 16x16x32: A[m=lane&15][k=8q+j], B[k=8q+j][n=lane&15], C[row=4q+r][col=lane&15]
// S^T = K*Q^T (M=kv,N=q,K=d): lane(c,qd) holds S^T[kv][q=c].
// Square in regs -> permlane re-tile -> K=32 PV; denominator via ones-column
// register-constant B operand.
//
// R7 vs R5(115.7us): KT 64 -> 128. Same total MFMA/VALU/LDS work, HALF the
// phase boundaries: 16 barriers (was 32), 16 staging bursts, 16 prefetch
// drains. LDS = K dbuf 32KB + V dbuf 32KB = 64KiB exactly (gfx950 allows
// 160KB/WG). Dn LDS exchange replaced by intra-wave __shfl. V staging is
// now 4x b128/thread (was 8x b64). K loads issue at iter top; V loads after
// the first compute sub-block (VGPR pressure relief, ~190 peak, cap 256).
// (R6 spilled: launch_bounds(512,4) capped 128 VGPR vs ~170 live. Reverted.)

__global__ __launch_bounds__(256, 2)
void powsm_attn(const float* __restrict__ qg, const float* __restrict__ kg,
                const float* __restrict__ vg, float* __restrict__ og)
{
    __shared__ __align__(16) short KsB[2][128][64];  // K tile [kv][d] bf16, swizzled
    __shared__ __align__(16) short VtB[2][64][128];  // V^T tile [d][kv] bf16, swizzled

    const int bh   = blockIdx.y;
    const int tid  = threadIdx.x;
    const int lane = tid & 63;
    const int wave = tid >> 6;
    const int qd   = lane >> 4;    // quad 0..3
    const int c    = lane & 15;

    const size_t base = (size_t)bh * N_CTX * DHEAD;
    const float* qp = qg + base;
    const float* kp = kg + base;
    const float* vp = vg + base;
    float*       op = og + base;

    const int qw0 = blockIdx.x * QBLK + wave * 64;

    // ---- denominator B-frag: B[k][n=c] = (c==0) ? 1.0bf16 : 0 ----
    union { uint4v u; short8 s; } dvu;
    {
        const unsigned ob = (c == 0) ? 0x3F803F80u : 0u;
        dvu.u[0] = ob; dvu.u[1] = ob; dvu.u[2] = ob; dvu.u[3] = ob;
    }
    const short8 bfden = dvu.s;

    // ---- hoist Q B-frags (16x16x32), SCALE folded in ----
    short8 Qf[4][2];
    #pragma unroll
    for (int qt = 0; qt < 4; ++qt) {
        #pragma unroll
        for (int ks = 0; ks < 2; ++ks) {
            const float* src = qp + (size_t)(qw0 + qt*16 + c) * DHEAD + ks*32 + qd*8;
            float4v a = *(const float4v*)(src);
            float4v b = *(const float4v*)(src + 4);
            uint4v u;
            u[0] = pack2(a[0]*SCALE_F, a[1]*SCALE_F);
            u[1] = pack2(a[2]*SCALE_F, a[3]*SCALE_F);
            u[2] = pack2(b[0]*SCALE_F, b[1]*SCALE_F);
            u[3] = pack2(b[2]*SCALE_F, b[3]*SCALE_F);
            union { uint4v u; short8 s; } cv; cv.u = u;
            Qf[qt][ks] = cv.s;
        }
    }

    float4v Oacc[4][4];            // [qt][nt]
    #pragma unroll
    for (int qt = 0; qt < 4; ++qt)
        #pragma unroll
        for (int nt = 0; nt < 4; ++nt)
            Oacc[qt][nt] = (float4v){0.f, 0.f, 0.f, 0.f};
    float4v Oden[4];               // denominator C-frag (col 0 = Σ P)
    #pragma unroll
    for (int qt = 0; qt < 4; ++qt) Oden[qt] = (float4v){0.f, 0.f, 0.f, 0.f};

    const int kr = tid >> 4;       // 0..15
    const int kc = tid & 15;       // 0..15

    float4v pK[8], pV[8];
    // ---- prologue: load + stage tile 0 into buffer 0 ----
    #pragma unroll
    for (int u = 0; u < 8; ++u)
        pK[u] = *(const float4v*)(kp + (size_t)(kr + u*16) * DHEAD + kc*4);
    #pragma unroll
    for (int j = 0; j < 8; ++j)
        pV[j] = *(const float4v*)(vp + (size_t)(8*kr + j) * DHEAD + kc*4);
    {
        short (*Ks)[64]  = KsB[0];
        short (*Vt)[128] = VtB[0];
        #pragma unroll
        for (int u = 0; u < 8; ++u) {
            const int row = kr + u*16;
            uint2v w; w[0] = pack2(pK[u][0], pK[u][1]); w[1] = pack2(pK[u][2], pK[u][3]);
            *(uint2v*)&Ks[row][swz(row, kc*4)] = w;
        }
        #pragma unroll
        for (int kk = 0; kk < 4; ++kk) {
            const int row = 4*kc + kk;
            uint4v w;
            w[0] = pack2(pV[0][kk], pV[1][kk]); w[1] = pack2(pV[2][kk], pV[3][kk]);
            w[2] = pack2(pV[4][kk], pV[5][kk]); w[3] = pack2(pV[6][kk], pV[7][kk]);
            *(uint4v*)&Vt[row][swz(row, 8*kr)] = w;
        }
    }
    __syncthreads();

    #pragma unroll 1
    for (int kvi = 0; kvi < NITER; ++kvi) {
        const int cur = kvi & 1;
        short (*Ks)[64]  = KsB[cur];
        short (*Vt)[128] = VtB[cur];

        // ---- issue next-tile K loads early ----
        if (kvi + 1 < NITER) {
            const float* kn = kp + (size_t)(kvi + 1) * KT * DHEAD;
            #pragma unroll
            for (int u = 0; u < 8; ++u)
                pK[u] = *(const float4v*)(kn + (size_t)(kr + u*16) * DHEAD + kc*4);
        }

        // ---- compute: 4 sub-blocks of 32 kv ----
        #pragma unroll
        for (int blk = 0; blk < 4; ++blk) {
            float4v slo[4], shi[4];
            #pragma unroll
            for (int qt = 0; qt < 4; ++qt) {
                slo[qt] = (float4v){0.f, 0.f, 0.f, 0.f};
                shi[qt] = (float4v){0.f, 0.f, 0.f, 0.f};
            }
            #pragma unroll
            for (int ks = 0; ks < 2; ++ks) {
                short8 afl = *(const short8*)&Ks[blk*32 + c][swz(c, ks*32 + qd*8)];
                #pragma unroll
                for (int qt = 0; qt < 4; ++qt)
                    slo[qt] = __builtin_amdgcn_mfma_f32_16x16x32_bf16(afl, Qf[qt][ks], slo[qt], 0, 0, 0);
            }
            #pragma unroll
            for (int ks = 0; ks < 2; ++ks) {
                short8 afh = *(const short8*)&Ks[blk*32 + 16 + c][swz(c, ks*32 + qd*8)];
                #pragma unroll
                for (int qt = 0; qt < 4; ++qt)
                    shi[qt] = __builtin_amdgcn_mfma_f32_16x16x32_bf16(afh, Qf[qt][ks], shi[qt], 0, 0, 0);
            }
            // ---- issue next-tile V loads after first sub-block ----
            if (blk == 0 && kvi + 1 < NITER) {
                const float* vn = vp + (size_t)(kvi + 1) * KT * DHEAD;
                #pragma unroll
                for (int j = 0; j < 8; ++j)
                    pV[j] = *(const float4v*)(vn + (size_t)(8*kr + j) * DHEAD + kc*4);
            }
            // square (vectorized) + pack + K32 re-tile (4 permlanes per qt)
            short8 pa[4];
            #pragma unroll
            for (int qt = 0; qt < 4; ++qt) {
                float4v psl = slo[qt] * slo[qt];
                float4v psh = shi[qt] * shi[qt];
                unsigned w00 = pack2(psl[0], psl[1]);   // (h=0,u=0)
                unsigned w01 = pack2(psl[2], psl[3]);   // (h=0,u=1)
                unsigned w10 = pack2(psh[0], psh[1]);   // (h=1,u=0)
                unsigned w11 = pack2(psh[2], psh[3]);   // (h=1,u=1)
                pl32(w00, w10);                 // lane-bit5 <-> h
                pl32(w01, w11);
                pl16(w00, w10);                 // lane-bit4 <-> g_hi
                pl16(w01, w11);
                union { uint4v u; short8 s; } cv;
                cv.u[0] = w00; cv.u[1] = w01; cv.u[2] = w10; cv.u[3] = w11;
                pa[qt] = cv.s;
            }
            // denominator: Σ P into col 0 (register-constant B operand)
            #pragma unroll
            for (int qt = 0; qt < 4; ++qt)
                Oden[qt] = __builtin_amdgcn_mfma_f32_16x16x32_bf16(pa[qt], bfden, Oden[qt], 0, 0, 0);
            // PV at K=32
            #pragma unroll
            for (int nt = 0; nt < 4; ++nt) {
                short8 bf = *(const short8*)&Vt[nt*16 + c][swz(c, blk*32 + qd*8)];
                #pragma unroll
                for (int qt = 0; qt < 4; ++qt)
                    Oacc[qt][nt] = __builtin_amdgcn_mfma_f32_16x16x32_bf16(pa[qt], bf, Oacc[qt][nt], 0, 0, 0);
            }
        }

        // ---- stage next tile into the other buffer (after compute) ----
        if (kvi + 1 < NITER) {
            short (*Kn)[64]  = KsB[cur ^ 1];
            short (*Vn)[128] = VtB[cur ^ 1];
            #pragma unroll
            for (int u = 0; u < 8; ++u) {
                const int row = kr + u*16;
                uint2v w; w[0] = pack2(pK[u][0], pK[u][1]); w[1] = pack2(pK[u][2], pK[u][3]);
                *(uint2v*)&Kn[row][swz(row, kc*4)] = w;
            }
            #pragma unroll
            for (int kk = 0; kk < 4; ++kk) {
                const int row = 4*kc + kk;
                uint4v w;
                w[0] = pack2(pV[0][kk], pV[1][kk]); w[1] = pack2(pV[2][kk], pV[3][kk]);
                w[2] = pack2(pV[4][kk], pV[5][kk]); w[3] = pack2(pV[6][kk], pV[7][kk]);
                *(uint4v*)&Vn[row][swz(row, 8*kr)] = w;
            }
        }
        __syncthreads();
    }

    // ---- epilogue: denominator broadcast via intra-wave shfl (no LDS) ----
    #pragma unroll
    for (int qt = 0; qt < 4; ++qt) {
        #pragma unroll
        for (int r = 0; r < 4; ++r) {
            float dsum = __shfl(Oden[qt][r], qd * 16);   // lane (qd,0) holds col 0
            float inv = 1.0f / (dsum + EPS_F);
            float* dst = op + (size_t)(qw0 + qt*16 + qd*4 + r) * DHEAD + c;
            #pragma unroll
            for (int nt = 0; nt < 4; ++nt)
                dst[nt*16] = Oacc[qt][nt][r] * inv;
        }
    }
}

extern "C" void kernel_launch(void* const* d_in, const int* in_sizes, int n_in,
                              void* d_out, int out_size, void* d_ws, size_t ws_size,
                              hipStream_t stream) {
    const float* q = (const float*)d_in[0];
    const float* k = (const float*)d_in[1];
    const float* v = (const float*)d_in[2];
    float* out = (float*)d_out;
    dim3 grid(N_CTX / QBLK, 64, 1);   // (8 q-tiles, B*H) = 512 blocks = 2/CU
    powsm_attn<<<grid, dim3(256, 1, 1), 0, stream>>>(q, k, v, out);
}

// Round 8
// 191.041 us; speedup vs baseline: 3.9858x; 1.1190x over previous
//
#include <hip/hip_runtime.h>

#define N_CTX 2048
#define DHEAD 64
#define SCALE_F 0.125f
#define EPS_F 1e-6f
#define KT 64
#define NITER (N_CTX / KT)
#define QBLK 256           // q per block: 4 waves x 64 q-rows

typedef __attribute__((ext_vector_type(8))) short short8;
typedef __attribute__((ext_vector_type(4))) float float4v;
typedef __attribute__((ext_vector_type(2))) unsigned uint2v;
typedef __attribute__((ext_vector_type(4))) unsigned uint4v;

// ---- bf16 pack ----
// R8 FIX: gfx950 has NO __builtin_amdgcn_cvt_pk_bf16_f32 (m240) — the old
// __has_builtin guard was always false, so every pack2 ran an ~11-VALU-op
// software rounding chain (~25% of iteration cycles, on the QK->pack->PV
// critical path). A scalar (__bf16) cast pair IS fused by the compiler into
// one v_cvt_pk_bf16_f32 (m240: casts beat inline asm) and rounds RNE,
// matching the old software path bit-for-bit.
#if defined(__HIP_DEVICE_COMPILE__)
__device__ __forceinline__ unsigned pack2(float a, float b) {
    union { __bf16 h[2]; unsigned u; } x;
    x.h[0] = (__bf16)a; x.h[1] = (__bf16)b;
    return x.u;
}
#else
__device__ __forceinline__ unsigned bf1(float f) {
    union { float f; unsigned u; } x; x.f = f;
    return (x.u + 0x7FFFu + ((x.u >> 16) & 1u)) >> 16;
}
__device__ __forceinline__ unsigned pack2(float a, float b) {
    return bf1(a) | (bf1(b) << 16);
}
#endif

// ---- gfx950 permlane swaps (K=16 C-layout -> K=32 A-frag re-tile) ----
#if defined(__HIP_DEVICE_COMPILE__) && __has_builtin(__builtin_amdgcn_permlane32_swap)
__device__ __forceinline__ void pl32(unsigned &x, unsigned &y) {
    uint2v r = __builtin_amdgcn_permlane32_swap(x, y, false, false);
    x = r[0]; y = r[1];
}
#else
__device__ __forceinline__ void pl32(unsigned &x, unsigned &y) {
    asm volatile("v_permlane32_swap_b32 %0, %1" : "+v"(x), "+v"(y));
}
#endif
#if defined(__HIP_DEVICE_COMPILE__) && __has_builtin(__builtin_amdgcn_permlane16_swap)
__device__ __forceinline__ void pl16(unsigned &x, unsigned &y) {
    uint2v r = __builtin_amdgcn_permlane16_swap(x, y, false, false);
    x = r[0]; y = r[1];
}
#else
__device__ __forceinline__ void pl16(unsigned &x, unsigned &y) {
    asm volatile("v_permlane16_swap_b32 %0, %1" : "+v"(x), "+v"(y));
}
#endif

// ---- LDS XOR swizzle (T2 / G4): unpadded [64][64] bf16 tiles (128B rows) ----
__device__ __forceinline__ int swz(int row, int col) {
    return col ^ ((row & 7) << 3);
}

// Layouts (gfx950, m89-verified):
//  mfma 16x16x32: A[m=lane&15][k=8q+j], B[k=8q+j][n=lane&15], C[row=4q+r][col=lane&15]
// S^T = K*Q^T (M=kv,N=q,K=d): lane(c,qd) holds S^T[kv][q=c].
// Square in regs -> permlane re-tile -> K=32 PV; denominator via ones-column
// register-constant B operand.
//
// R8 = R5 structure (115.7us: KT=64, XOR swizzle, K=32 PV, ones-column
// denominator, no setprio) + HW cvt_pk fix above. Single-variable change.
// (R7 KT=128: 121us, falsified phase-boundary theory. R6: VGPR spill, void.)

__global__ __launch_bounds__(256, 2)
void powsm_attn(const float* __restrict__ qg, const float* __restrict__ kg,
                const float* __restrict__ vg, float* __restrict__ og)
{
    __shared__ __align__(16) short KsB[2][64][64];  // K tile row-major bf16, swizzled
    __shared__ __align__(16) short VtB[2][64][64];  // V^T tile Vt[d][kv], swizzled
    __shared__ float Dn[4][64];                     // denominator exchange

    const int bh   = blockIdx.y;
    const int tid  = threadIdx.x;
    const int wave = tid >> 6;
    const int lane = tid & 63;
    const int qd   = lane >> 4;    // quad 0..3
    const int c    = lane & 15;

    const size_t base = (size_t)bh * N_CTX * DHEAD;
    const float* qp = qg + base;
    const float* kp = kg + base;
    const float* vp = vg + base;
    float*       op = og + base;

    const int qw0 = blockIdx.x * QBLK + wave * 64;

    // ---- denominator B-frag: B[k][n=c] = (c==0) ? 1.0bf16 : 0 ----
    union { uint4v u; short8 s; } dvu;
    {
        const unsigned ob = (c == 0) ? 0x3F803F80u : 0u;
        dvu.u[0] = ob; dvu.u[1] = ob; dvu.u[2] = ob; dvu.u[3] = ob;
    }
    const short8 bfden = dvu.s;

    // ---- hoist Q B-frags (16x16x32), SCALE folded in ----
    short8 Qf[4][2];
    #pragma unroll
    for (int qt = 0; qt < 4; ++qt) {
        #pragma unroll
        for (int ks = 0; ks < 2; ++ks) {
            const float* src = qp + (size_t)(qw0 + qt*16 + c) * DHEAD + ks*32 + qd*8;
            float4v a = *(const float4v*)(src);
            float4v b = *(const float4v*)(src + 4);
            uint4v u;
            u[0] = pack2(a[0]*SCALE_F, a[1]*SCALE_F);
            u[1] = pack2(a[2]*SCALE_F, a[3]*SCALE_F);
            u[2] = pack2(b[0]*SCALE_F, b[1]*SCALE_F);
            u[3] = pack2(b[2]*SCALE_F, b[3]*SCALE_F);
            union { uint4v u; short8 s; } cv; cv.u = u;
            Qf[qt][ks] = cv.s;
        }
    }

    float4v Oacc[4][4];            // [qt][nt]
    #pragma unroll
    for (int qt = 0; qt < 4; ++qt)
        #pragma unroll
        for (int nt = 0; nt < 4; ++nt)
            Oacc[qt][nt] = (float4v){0.f, 0.f, 0.f, 0.f};
    float4v Oden[4];               // denominator C-frag (col 0 = Σ P)
    #pragma unroll
    for (int qt = 0; qt < 4; ++qt) Oden[qt] = (float4v){0.f, 0.f, 0.f, 0.f};

    const int kr = tid >> 4;       // K-stage row (+u*16), V 4-row group
    const int kc = tid & 15;       // col group

    // ---- load tile 0 + prologue stage into buf0 ----
    float4v pK[4], pV[4];
    #pragma unroll
    for (int u = 0; u < 4; ++u)
        pK[u] = *(const float4v*)(kp + (size_t)(kr + u*16) * DHEAD + kc*4);
    #pragma unroll
    for (int j = 0; j < 4; ++j)
        pV[j] = *(const float4v*)(vp + (size_t)(4*kr + j) * DHEAD + kc*4);

    {
        short (*Ks)[64] = KsB[0];
        short (*Vt)[64] = VtB[0];
        #pragma unroll
        for (int u = 0; u < 4; ++u) {
            const int row = kr + u*16;
            uint2v w; w[0] = pack2(pK[u][0], pK[u][1]); w[1] = pack2(pK[u][2], pK[u][3]);
            *(uint2v*)&Ks[row][swz(row, kc*4)] = w;
        }
        #pragma unroll
        for (int kk = 0; kk < 4; ++kk) {
            const int row = 4*kc + kk;
            uint2v w; w[0] = pack2(pV[0][kk], pV[1][kk]); w[1] = pack2(pV[2][kk], pV[3][kk]);
            *(uint2v*)&Vt[row][swz(row, 4*kr)] = w;
        }
    }
    __syncthreads();

    #pragma unroll 1
    for (int kvi = 0; kvi < NITER; ++kvi) {
        const int cur = kvi & 1;
        short (*Ks)[64] = KsB[cur];
        short (*Vt)[64] = VtB[cur];

        // ---- issue next-tile loads early (land during compute) ----
        if (kvi + 1 < NITER) {
            const float* kn = kp + (size_t)(kvi + 1) * KT * DHEAD;
            const float* vn = vp + (size_t)(kvi + 1) * KT * DHEAD;
            #pragma unroll
            for (int u = 0; u < 4; ++u)
                pK[u] = *(const float4v*)(kn + (size_t)(kr + u*16) * DHEAD + kc*4);
            #pragma unroll
            for (int j = 0; j < 4; ++j)
                pV[j] = *(const float4v*)(vn + (size_t)(4*kr + j) * DHEAD + kc*4);
        }

        // ---- compute: per 32-kv block ----
        #pragma unroll
        for (int blk = 0; blk < 2; ++blk) {
            float4v slo[4], shi[4];
            #pragma unroll
            for (int qt = 0; qt < 4; ++qt) {
                slo[qt] = (float4v){0.f, 0.f, 0.f, 0.f};
                shi[qt] = (float4v){0.f, 0.f, 0.f, 0.f};
            }
            #pragma unroll
            for (int ks = 0; ks < 2; ++ks) {
                short8 afl = *(const short8*)&Ks[blk*32 + c][swz(c, ks*32 + qd*8)];
                #pragma unroll
                for (int qt = 0; qt < 4; ++qt)
                    slo[qt] = __builtin_amdgcn_mfma_f32_16x16x32_bf16(afl, Qf[qt][ks], slo[qt], 0, 0, 0);
            }
            #pragma unroll
            for (int ks = 0; ks < 2; ++ks) {
                short8 afh = *(const short8*)&Ks[blk*32 + 16 + c][swz(c, ks*32 + qd*8)];
                #pragma unroll
                for (int qt = 0; qt < 4; ++qt)
                    shi[qt] = __builtin_amdgcn_mfma_f32_16x16x32_bf16(afh, Qf[qt][ks], shi[qt], 0, 0, 0);
            }
            // square (vectorized) + pack + K32 re-tile (4 permlanes per qt)
            short8 pa[4];
            #pragma unroll
            for (int qt = 0; qt < 4; ++qt) {
                float4v psl = slo[qt] * slo[qt];
                float4v psh = shi[qt] * shi[qt];
                unsigned w00 = pack2(psl[0], psl[1]);   // (h=0,u=0)
                unsigned w01 = pack2(psl[2], psl[3]);   // (h=0,u=1)
                unsigned w10 = pack2(psh[0], psh[1]);   // (h=1,u=0)
                unsigned w11 = pack2(psh[2], psh[3]);   // (h=1,u=1)
                pl32(w00, w10);                 // lane-bit5 <-> h
                pl32(w01, w11);
                pl16(w00, w10);                 // lane-bit4 <-> g_hi
                pl16(w01, w11);
                union { uint4v u; short8 s; } cv;
                cv.u[0] = w00; cv.u[1] = w01; cv.u[2] = w10; cv.u[3] = w11;
                pa[qt] = cv.s;
            }
            // denominator: Σ P into col 0 (register-constant B operand)
            #pragma unroll
            for (int qt = 0; qt < 4; ++qt)
                Oden[qt] = __builtin_amdgcn_mfma_f32_16x16x32_bf16(pa[qt], bfden, Oden[qt], 0, 0, 0);
            // PV at K=32
            #pragma unroll
            for (int nt = 0; nt < 4; ++nt) {
                short8 bf = *(const short8*)&Vt[nt*16 + c][swz(c, blk*32 + qd*8)];
                #pragma unroll
                for (int qt = 0; qt < 4; ++qt)
                    Oacc[qt][nt] = __builtin_amdgcn_mfma_f32_16x16x32_bf16(pa[qt], bf, Oacc[qt][nt], 0, 0, 0);
            }
        }

        // ---- stage next tile into the other buffer (after compute) ----
        if (kvi + 1 < NITER) {
            short (*Kn)[64] = KsB[cur ^ 1];
            short (*Vn)[64] = VtB[cur ^ 1];
            #pragma unroll
            for (int u = 0; u < 4; ++u) {
                const int row = kr + u*16;
                uint2v w; w[0] = pack2(pK[u][0], pK[u][1]); w[1] = pack2(pK[u][2], pK[u][3]);
                *(uint2v*)&Kn[row][swz(row, kc*4)] = w;
            }
            #pragma unroll
            for (int kk = 0; kk < 4; ++kk) {
                const int row = 4*kc + kk;
                uint2v w; w[0] = pack2(pV[0][kk], pV[1][kk]); w[1] = pack2(pV[2][kk], pV[3][kk]);
                *(uint2v*)&Vn[row][swz(row, 4*kr)] = w;
            }
        }
        __syncthreads();
    }

    // ---- denominator exchange: lanes c==0 hold col 0 of the C-frag ----
    if (c == 0) {
        #pragma unroll
        for (int qt = 0; qt < 4; ++qt)
            #pragma unroll
            for (int r = 0; r < 4; ++r)
                Dn[wave][qt*16 + qd*4 + r] = Oden[qt][r];
    }
    __syncthreads();

    // ---- epilogue ----
    #pragma unroll
    for (int qt = 0; qt < 4; ++qt) {
        #pragma unroll
        for (int r = 0; r < 4; ++r) {
            float inv = 1.0f / (Dn[wave][qt*16 + qd*4 + r] + EPS_F);
            float* dst = op + (size_t)(qw0 + qt*16 + qd*4 + r) * DHEAD + c;
            #pragma unroll
            for (int nt = 0; nt < 4; ++nt)
                dst[nt*16] = Oacc[qt][nt][r] * inv;
        }
    }
}

extern "C" void kernel_launch(void* const* d_in, const int* in_sizes, int n_in,
                              void* d_out, int out_size, void* d_ws, size_t ws_size,
                              hipStream_t stream) {
    const float* q = (const float*)d_in[0];
    const float* k = (const float*)d_in[1];
    const float* v = (const float*)d_in[2];
    float* out = (float*)d_out;
    dim3 grid(N_CTX / QBLK, 64, 1);   // (8 q-tiles, B*H) = 512 blocks = 2/CU
    powsm_attn<<<grid, dim3(256, 1, 1), 0, stream>>>(q, k, v, out);
}